// Round 9
// baseline (24.179 us; speedup 1.0000x reference)
//
#include <hip/hip_runtime.h>
#include <hip/hip_fp16.h>
#include <math.h>

#define D 64
#define NS 64      // S: tokens per shard
#define H 8
#define NSHARD 128 // B * n_shards
#define KPB 16     // k columns per block, 1 per wave (16 waves)
#define NBLK (NSHARD * (D / KPB))   // 512 blocks x 1024 thr = 2 blocks/CU, 32 waves/CU (MAX)
#define NTHR 1024
#define TBL 512    // LUT entries over [-8, 8), nearest-neighbor (centers baked)
constexpr float LR = 0.01f;
constexpr float WD = 0.01f;
constexpr float GSCALE = (float)TBL / 16.0f;   // 32 entries per unit g
constexpr float GOFF   = 8.0f * GSCALE;        // 256
constexpr float TMAXN  = 511.0f;               // clamp for nearest index

typedef __attribute__((ext_vector_type(8))) short bf16x8;  // 8 bf16 (4 VGPR)
typedef __attribute__((ext_vector_type(4))) float f32x4;

__device__ __forceinline__ short f2bf(float f) {           // f32 -> bf16 RNE
    unsigned u = __float_as_uint(f);
    return (short)((u + 0x7FFF + ((u >> 16) & 1)) >> 16);
}

template<int CTRL, int RM>
__device__ __forceinline__ float dpp_add(float v) {
    int t = __builtin_amdgcn_update_dpp(0, __float_as_int(v), CTRL, RM, 0xf, true);
    return v + __int_as_float(t);
}

// LDS layout (35584 B, 2 blocks/CU; no overlays):
//   [0,    11520): WT[80][72] bf16 -- rows 0-15: W0^T E-tile cols (this block's 16),
//                                    rows 16-79: Wq^T all 64 cols
//   [11520,28928): XQT[64 j][68 s] u32 (half2(x,q))
//   [28928,33536): Esm[64 s][18] f32 (cols 0-15 = this block's E cols, GSCALE-baked)
//   [33536,35584): Tl[512] f32 (nearest LUT, cell centers)
#define OFF_XQT  11520
#define OFF_ESM  28928
#define OFF_TL   33536
#define SM_BYTES 35584
#define ESM_S    18

__global__ __launch_bounds__(NTHR, 8) void tnt_fused(const float* __restrict__ X,
                                                     const float* __restrict__ mem0,
                                                     const float* __restrict__ opt,
                                                     const float* __restrict__ Wq,
                                                     float* __restrict__ out) {
    __shared__ __align__(16) char smem[SM_BYTES];
    short*    WT   = (short*)(smem);
    unsigned* XQT  = (unsigned*)(smem + OFF_XQT);
    float*    EsmF = (float*)(smem + OFF_ESM);
    float*    Tl   = (float*)(smem + OFF_TL);

    // XCD swizzle: the 4 blocks of a shard land on one XCD's L2 (512 % 8 == 0)
    const int bid  = ((int)blockIdx.x & 7) * (NBLK / 8) + ((int)blockIdx.x >> 3);
    const int n    = bid >> 2;
    const int kq   = bid & 3;
    const int tid  = threadIdx.x;
    const int wv   = tid >> 6;            // 0..15
    const int lane = tid & 63;
    const int rg   = wv & 3;              // GEMM row-group (16 rows each)
    const int l15  = lane & 15, lhi = lane >> 4;
    const int k0   = (kq << 4) + wv;      // this wave's k column

    const float* Xs = X + n * NS * D;

    // ---- phase 1: stage W0^T E-tile (16 cols) + Wq^T (64 cols) ----
    if (tid < 640) {                       // 640 bf16x8 packs, one per thread
        const int  isq    = tid >= 128;
        const int  tt     = isq ? tid - 128 : tid;
        const int  colsrc = isq ? (tt & 63) : ((kq << 4) + (tt & 15));
        const int  rowdst = isq ? (16 + (tt & 63)) : (tt & 15);
        const int  g      = isq ? (tt >> 6) : (tt >> 4);
        const float* Wm   = isq ? Wq : mem0;
        bf16x8 pk;
#pragma unroll
        for (int i = 0; i < 8; ++i)
            pk[i] = f2bf(Wm[(g * 8 + i) * D + colsrc]);   // coalesced per i
        *(bf16x8*)(WT + rowdst * 72 + g * 8) = pk;
    }
    // A-frags (rows rg*16 + l15) for the GEMM waves only
    bf16x8 afrag[2];
    if (wv < 12) {
        const float* xrow = Xs + (rg * 16 + l15) * D + lhi * 8;
#pragma unroll
        for (int ks = 0; ks < 2; ++ks) {
            const float4 u0 = *(const float4*)(xrow + ks * 32);
            const float4 u1 = *(const float4*)(xrow + ks * 32 + 4);
            bf16x8 a;
            a[0]=f2bf(u0.x); a[1]=f2bf(u0.y); a[2]=f2bf(u0.z); a[3]=f2bf(u0.w);
            a[4]=f2bf(u1.x); a[5]=f2bf(u1.y); a[6]=f2bf(u1.z); a[7]=f2bf(u1.w);
            afrag[ks] = a;
        }
    }
    const float m0v  = mem0[lane * D + k0];
    const float wdm0 = WD * m0v;
    __syncthreads();

    // ---- phase 2 (3-way wave split): Q GEMM | E tile | LUT ----
    if (wv < 8) {
        // Q GEMM: this wave does 2 nt-tiles (ntb, ntb+1) for row-group rg
        const int ntb = (wv >> 2) << 1;
        f32x4 accQ[2];
        accQ[0] = 0; accQ[1] = 0;
#pragma unroll
        for (int i = 0; i < 2; ++i) {
            const int col = (ntb + i) * 16 + l15;
#pragma unroll
            for (int ks = 0; ks < 2; ++ks) {
                const bf16x8 b1 = *(const bf16x8*)(WT + (16 + col) * 72 + ks * 32 + lhi * 8);
                accQ[i] = __builtin_amdgcn_mfma_f32_16x16x32_bf16(afrag[ks], b1, accQ[i], 0,0,0);
            }
        }
        // XQT epilogue: half2(x, q), row=j(col), col=s layout
#pragma unroll
        for (int i = 0; i < 2; ++i) {
#pragma unroll
            for (int r = 0; r < 4; ++r) {
                const int row = rg * 16 + lhi * 4 + r;      // s
                const int col = (ntb + i) * 16 + l15;       // j
                const __half2 h = __halves2half2(__float2half_rn(Xs[row * D + col]),
                                                 __float2half_rn(accQ[i][r]));
                XQT[col * 68 + row] = *(const unsigned*)&h;
            }
        }
    } else if (wv < 12) {
        // E tile: this block's 16 k-cols, row-group rg
        f32x4 accE = 0;
#pragma unroll
        for (int ks = 0; ks < 2; ++ks) {
            const bf16x8 b0 = *(const bf16x8*)(WT + l15 * 72 + ks * 32 + lhi * 8);
            accE = __builtin_amdgcn_mfma_f32_16x16x32_bf16(afrag[ks], b0, accE, 0,0,0);
        }
        const float c = (2.0f / (float)D) * GSCALE;
        const int ecol = (kq << 4) + l15;
#pragma unroll
        for (int r = 0; r < 4; ++r) {
            const int row = rg * 16 + lhi * 4 + r;
            EsmF[row * ESM_S + l15] = c * (accE[r] - Xs[row * D + ecol]);
        }
    } else {
        // LR-scaled nearest LUT (waves 12-15 = 256 threads, 2 entries each)
        float w1d[H], b1d[H], w2[H];
#pragma unroll
        for (int h = 0; h < H; ++h) {
            w1d[h] = 2.0f * opt[h]; b1d[h] = 2.0f * opt[H + h]; w2[h] = opt[2 * H + h];
        }
        const float b2 = opt[3 * H];
        const int base = (wv - 12) * 64 + lane;   // 0..255
#pragma unroll
        for (int jj = base; jj < TBL; jj += 256) {
            const float g = ((float)jj + 0.5f - GOFF) / GSCALE;
            float acc = b2;
#pragma unroll
            for (int h = 0; h < H; ++h) {
                const float u = __expf(fmaf(w1d[h], g, b1d[h]));   // e^{2y}
                acc = fmaf(w2[h], (u - 1.0f) * __builtin_amdgcn_rcpf(u + 1.0f), acc);
            }
            Tl[jj] = LR * acc;
        }
    }
    __syncthreads();   // XQT + Esm + Tl ready

    const float e0 = EsmF[lane * ESM_S + wv];  // E[n, s=lane, k0] * GSCALE

    // ---- main loop: 8 fully-unrolled batches; in-wave 64-lane reduce; scatter ----
    const unsigned* xrow = XQT + lane * 68;    // this lane's j-column, along s
    float cum = m0v;
    const int  bp32 = ((lane ^ 32) << 2);      // ds_bpermute byte index for xor32
    const bool s1 = (lane & 1) != 0;
    const bool s2 = (lane & 2) != 0;
    const bool s4 = (lane & 4) != 0;
    float* orow = out + n * NS * D + k0;

#pragma unroll
    for (int b = 0; b < 8; ++b) {
        const uint4 xa = *(const uint4*)(xrow + b * 8);
        const uint4 xb = *(const uint4*)(xrow + b * 8 + 4);
        const unsigned xw[8] = {xa.x, xa.y, xa.z, xa.w, xb.x, xb.y, xb.z, xb.w};
        float q8[8], v8[8];
#pragma unroll
        for (int u = 0; u < 8; ++u) {          // independent across u
            const int s = (b << 3) + u;
            const float ek = __int_as_float(
                __builtin_amdgcn_readlane(__float_as_int(e0), s));
            const __half2 hv = *(const __half2*)&xw[u];
            const float xv = __low2float(hv);
            q8[u] = __high2float(hv);
            const float t = __builtin_amdgcn_fmed3f(fmaf(xv, ek, GOFF), 0.0f, TMAXN);
            v8[u] = Tl[(int)t] + wdm0;         // single b32 gather per u
        }
        float p8[8];
#pragma unroll
        for (int u = 0; u < 8; ++u) {          // serial cum chain + row-16 DPP reduce
            cum -= v8[u];
            float p = q8[u] * cum;
            p = dpp_add<0xB1,  0xf>(p);        // xor 1
            p = dpp_add<0x4E,  0xf>(p);        // xor 2
            p = dpp_add<0x141, 0xf>(p);        // row_half_mirror -> 8-sum
            p = dpp_add<0x140, 0xf>(p);        // row_mirror      -> 16-sum
            p8[u] = p;
        }
        // per-lane select: lane picks u = lane&7 (7 cndmask, static idx)
        const float t0 = s1 ? p8[1] : p8[0];
        const float t1 = s1 ? p8[3] : p8[2];
        const float t2 = s1 ? p8[5] : p8[4];
        const float t3 = s1 ? p8[7] : p8[6];
        const float a0 = s2 ? t1 : t0;
        const float a1 = s2 ? t3 : t2;
        float val = s4 ? a1 : a0;
        // cross-row sum: xor16 (ds_swizzle) + xor32 (ds_bpermute)
        val += __int_as_float(__builtin_amdgcn_ds_swizzle(__float_as_int(val), 0x401F));
        val += __int_as_float(__builtin_amdgcn_ds_bpermute(bp32, __float_as_int(val)));
        if (lane < 8)                          // lanes 0..7 hold full sums for u=lane
            orow[((b << 3) + lane) * D] = val;
    }
}

extern "C" void kernel_launch(void* const* d_in, const int* in_sizes, int n_in,
                              void* d_out, int out_size, void* d_ws, size_t ws_size,
                              hipStream_t stream) {
    const float* X    = (const float*)d_in[0];   // (4,2048,64)
    const float* mem0 = (const float*)d_in[1];   // (4096,)
    const float* opt  = (const float*)d_in[2];   // (25,)
    const float* Wq   = (const float*)d_in[3];   // (64,64)
    float* out = (float*)d_out;

    tnt_fused<<<dim3(NBLK), dim3(NTHR), 0, stream>>>(X, mem0, opt, Wq, out);
}

// Round 10
// 21.654 us; speedup vs baseline: 1.1166x; 1.1166x over previous
//
#include <hip/hip_runtime.h>
#include <hip/hip_fp16.h>
#include <math.h>

#define D 64
#define NS 64      // S: tokens per shard
#define H 8
#define NSHARD 128 // B * n_shards
#define KPB 16     // k columns per block (2 per wave, 8 waves)
#define NBLK (NSHARD * (D / KPB))   // 512 blocks = 2/CU exactly
#define NTHR 512
#define TBL 512    // LUT entries over [-8, 8), nearest-neighbor (centers baked)
constexpr float LR = 0.01f;
constexpr float WD = 0.01f;
constexpr float GSCALE = (float)TBL / 16.0f;   // 32 entries per unit g
constexpr float GOFF   = 8.0f * GSCALE;        // 256
constexpr float TMAXN  = 511.0f;               // clamp for nearest index

typedef __attribute__((ext_vector_type(8))) short bf16x8;  // 8 bf16 (4 VGPR)
typedef __attribute__((ext_vector_type(4))) float f32x4;
typedef __attribute__((ext_vector_type(2))) float f32x2;   // -> v_pk_*_f32

__device__ __forceinline__ short f2bf(float f) {           // f32 -> bf16 RNE
    unsigned u = __float_as_uint(f);
    return (short)((u + 0x7FFF + ((u >> 16) & 1)) >> 16);
}

// packed DPP butterfly stage: 2 x v_mov_dpp + 1 x v_pk_add_f32 (3 instr vs 4)
template<int CTRL>
__device__ __forceinline__ f32x2 pkdpp_add(f32x2 v) {
    const int tx = __builtin_amdgcn_update_dpp(0, __float_as_int(v.x), CTRL, 0xf, 0xf, true);
    const int ty = __builtin_amdgcn_update_dpp(0, __float_as_int(v.y), CTRL, 0xf, 0xf, true);
    f32x2 t; t.x = __int_as_float(tx); t.y = __int_as_float(ty);
    return v + t;                              // v_pk_add_f32
}

// LDS layout (72704 B, 2 blocks/CU: 2x72704 = 145408 <= 163840; no overlays):
//   [0,    11520): WT[80][72] bf16 -- rows 0-15: W0^T E-tile cols (this block's 16),
//                                    rows 16-79: Wq^T all 64 cols
//   [11520,28928): XQT[64 j][68 s] u32 (half2(x,q))
//   [28928,33536): Esm[64 s][18] f32 (cols 0-15 = this block's E cols, GSCALE-baked)
//   [33536,35584): Tl[512] f32 (nearest LUT, cell centers)
//   [35584,72704): o4[8][1160] f32 -- 8 row-copies x 64 s x 18 (16 k-cols + pad)
#define OFF_XQT  11520
#define OFF_ESM  28928
#define OFF_TL   33536
#define OFF_O4   35584
#define SM_BYTES 72704
#define O4_R     1160
#define O4_S     18
#define ESM_S    18

__global__ __launch_bounds__(NTHR, 4) void tnt_fused(const float* __restrict__ X,
                                                     const float* __restrict__ mem0,
                                                     const float* __restrict__ opt,
                                                     const float* __restrict__ Wq,
                                                     float* __restrict__ out) {
    __shared__ __align__(16) char smem[SM_BYTES];
    short*    WT   = (short*)(smem);
    unsigned* XQT  = (unsigned*)(smem + OFF_XQT);
    float*    EsmF = (float*)(smem + OFF_ESM);
    float*    Tl   = (float*)(smem + OFF_TL);
    float*    o4   = (float*)(smem + OFF_O4);

    // XCD swizzle: the 4 blocks of a shard land on one XCD's L2 (512 % 8 == 0)
    const int bid  = ((int)blockIdx.x & 7) * (NBLK / 8) + ((int)blockIdx.x >> 3);
    const int n    = bid >> 2;
    const int kq   = bid & 3;
    const int tid  = threadIdx.x;
    const int wv   = tid >> 6;            // 0..7
    const int lane = tid & 63;
    const int rg   = wv & 3;              // GEMM row-group (16 rows each)
    const int l15  = lane & 15, lhi = lane >> 4;
    const int k0   = (kq << 4) + (wv << 1);   // this wave's first k column

    const float* Xs = X + n * NS * D;

    // ---- phase 1: stage W0^T E-tile (16 cols) + Wq^T (64 cols) ----
    // 640 bf16x8 packs over 512 threads (threads 0-127 do two)
    for (int t = tid; t < 640; t += NTHR) {
        const int  isq    = t >= 128;
        const int  tt     = isq ? t - 128 : t;
        const int  colsrc = isq ? (tt & 63) : ((kq << 4) + (tt & 15));
        const int  rowdst = isq ? (16 + (tt & 63)) : (tt & 15);
        const int  g      = isq ? (tt >> 6) : (tt >> 4);
        const float* Wm   = isq ? Wq : mem0;
        bf16x8 pk;
#pragma unroll
        for (int i = 0; i < 8; ++i)
            pk[i] = f2bf(Wm[(g * 8 + i) * D + colsrc]);   // coalesced per i
        *(bf16x8*)(WT + rowdst * 72 + g * 8) = pk;
    }
    // A-frags (rows rg*16 + l15), used by this wave's GEMM half
    bf16x8 afrag[2];
    {
        const float* xrow = Xs + (rg * 16 + l15) * D + lhi * 8;
#pragma unroll
        for (int ks = 0; ks < 2; ++ks) {
            const float4 u0 = *(const float4*)(xrow + ks * 32);
            const float4 u1 = *(const float4*)(xrow + ks * 32 + 4);
            bf16x8 a;
            a[0]=f2bf(u0.x); a[1]=f2bf(u0.y); a[2]=f2bf(u0.z); a[3]=f2bf(u0.w);
            a[4]=f2bf(u1.x); a[5]=f2bf(u1.y); a[6]=f2bf(u1.z); a[7]=f2bf(u1.w);
            afrag[ks] = a;
        }
    }
    const float2 m0v = *(const float2*)(mem0 + lane * D + k0);  // both k-cols
    const f32x2 wdm2 = {WD * m0v.x, WD * m0v.y};
    __syncthreads();

    // ---- phase 2 (split): waves 0-3 Q GEMM + XQT; waves 4-7 E tile + LUT ----
    if (wv < 4) {
        f32x4 accQ[4];
#pragma unroll
        for (int nt = 0; nt < 4; ++nt) accQ[nt] = 0;
#pragma unroll
        for (int nt = 0; nt < 4; ++nt) {
            const int col = nt * 16 + l15;
#pragma unroll
            for (int ks = 0; ks < 2; ++ks) {
                const bf16x8 b1 = *(const bf16x8*)(WT + (16 + col) * 72 + ks * 32 + lhi * 8);
                accQ[nt] = __builtin_amdgcn_mfma_f32_16x16x32_bf16(afrag[ks], b1, accQ[nt], 0,0,0);
            }
        }
        // XQT epilogue: half2(x, q), row=j(col), col=s layout
#pragma unroll
        for (int nt = 0; nt < 4; ++nt) {
#pragma unroll
            for (int r = 0; r < 4; ++r) {
                const int row = rg * 16 + lhi * 4 + r;      // s
                const int col = nt * 16 + l15;              // j
                const __half2 h = __halves2half2(__float2half_rn(Xs[row * D + col]),
                                                 __float2half_rn(accQ[nt][r]));
                XQT[col * 68 + row] = *(const unsigned*)&h;
            }
        }
    } else {
        f32x4 accE = 0;
#pragma unroll
        for (int ks = 0; ks < 2; ++ks) {
            const bf16x8 b0 = *(const bf16x8*)(WT + l15 * 72 + ks * 32 + lhi * 8);
            accE = __builtin_amdgcn_mfma_f32_16x16x32_bf16(afrag[ks], b0, accE, 0,0,0);
        }
        const float c = (2.0f / (float)D) * GSCALE;
        const int ecol = (kq << 4) + l15;
#pragma unroll
        for (int r = 0; r < 4; ++r) {
            const int row = rg * 16 + lhi * 4 + r;
            EsmF[row * ESM_S + l15] = c * (accE[r] - Xs[row * D + ecol]);
        }
        // LR-scaled nearest LUT (256 threads, 2 entries each)
        float w1d[H], b1d[H], w2[H];
#pragma unroll
        for (int h = 0; h < H; ++h) {
            w1d[h] = 2.0f * opt[h]; b1d[h] = 2.0f * opt[H + h]; w2[h] = opt[2 * H + h];
        }
        const float b2 = opt[3 * H];
        const int base = tid - 256;            // 0..255
#pragma unroll
        for (int jj = base; jj < TBL; jj += 256) {
            const float g = ((float)jj + 0.5f - GOFF) / GSCALE;
            float acc = b2;
#pragma unroll
            for (int h = 0; h < H; ++h) {
                const float u = __expf(fmaf(w1d[h], g, b1d[h]));   // e^{2y}
                acc = fmaf(w2[h], (u - 1.0f) * __builtin_amdgcn_rcpf(u + 1.0f), acc);
            }
            Tl[jj] = LR * acc;
        }
    }
    __syncthreads();   // XQT + Esm + Tl ready

    const float2 ee = *(const float2*)(EsmF + lane * ESM_S + (wv << 1));
    const float e0 = ee.x;     // E[n, s=lane, k0]   * GSCALE
    const float e1 = ee.y;     // E[n, s=lane, k0+1] * GSCALE

    // ---- main loop: 8 fully-unrolled batches; 3-stage pk-DPP; 1 b64 write/batch ----
    const unsigned* xrow = XQT + lane * 68;    // this lane's j-column, along s
    f32x2 cum = {m0v.x, m0v.y};

    // lane -> (row-copy g8 = lane>>3, step u = lane&7); k-pair written together
    const bool s1 = (lane & 1) != 0;
    const bool s2 = (lane & 2) != 0;
    const bool s4 = (lane & 4) != 0;
    float* wbase = o4 + (lane >> 3) * O4_R + (lane & 7) * O4_S + (wv << 1);

#pragma unroll
    for (int b = 0; b < 8; ++b) {
        const uint4 xa = *(const uint4*)(xrow + b * 8);
        const uint4 xb = *(const uint4*)(xrow + b * 8 + 4);
        const unsigned xw[8] = {xa.x, xa.y, xa.z, xa.w, xb.x, xb.y, xb.z, xb.w};
        float q8[8];
        f32x2 v01[8];
#pragma unroll
        for (int u = 0; u < 8; ++u) {          // independent across u AND k
            const int s = (b << 3) + u;
            const float ek0 = __int_as_float(
                __builtin_amdgcn_readlane(__float_as_int(e0), s));
            const float ek1 = __int_as_float(
                __builtin_amdgcn_readlane(__float_as_int(e1), s));
            const __half2 hv = *(const __half2*)&xw[u];
            const float xv = __low2float(hv);
            q8[u] = __high2float(hv);
            const float t0 = __builtin_amdgcn_fmed3f(fmaf(xv, ek0, GOFF), 0.0f, TMAXN);
            const float t1 = __builtin_amdgcn_fmed3f(fmaf(xv, ek1, GOFF), 0.0f, TMAXN);
            f32x2 g2; g2.x = Tl[(int)t0]; g2.y = Tl[(int)t1];   // b32 gathers
            v01[u] = g2 + wdm2;                // v_pk_add_f32
        }
        f32x2 ps[8];
#pragma unroll
        for (int u = 0; u < 8; ++u) {          // chain + 3-stage packed DPP reduce
            cum = cum - v01[u];                // v_pk_add_f32 (neg)
            f32x2 qq; qq.x = q8[u]; qq.y = q8[u];
            f32x2 p = qq * cum;                // v_pk_mul_f32
            p = pkdpp_add<0xB1>(p);            // xor 1
            p = pkdpp_add<0x4E>(p);            // xor 2
            p = pkdpp_add<0x141>(p);           // half-mirror -> 8-lane-group sum
            ps[u] = p;
        }
        // per-lane select of its u = lane&7 pair (3-level ternary on f32x2)
        const f32x2 t0_ = s1 ? ps[1] : ps[0];
        const f32x2 t1_ = s1 ? ps[3] : ps[2];
        const f32x2 t2_ = s1 ? ps[5] : ps[4];
        const f32x2 t3_ = s1 ? ps[7] : ps[6];
        const f32x2 a0 = s2 ? t1_ : t0_;
        const f32x2 a1 = s2 ? t3_ : t2_;
        const f32x2 val = s4 ? a1 : a0;
        *(float2*)(wbase + b * (8 * O4_S)) = make_float2(val.x, val.y);  // ds_write_b64
    }

    __syncthreads();
    // epilogue: sum the 8 row-copies; 2 floats per thread (b64 reads/store)
    const int s_ = tid >> 3;                   // 0..63
    const int c2 = (tid & 7) << 1;             // 0,2,..,14
    float ox = 0.0f, oy = 0.0f;
#pragma unroll
    for (int r = 0; r < 8; ++r) {
        const float2 v = *(const float2*)(o4 + r * O4_R + s_ * O4_S + c2);
        ox += v.x; oy += v.y;
    }
    *(float2*)(out + (n * NS + s_) * D + (kq << 4) + c2) = make_float2(ox, oy);
}

extern "C" void kernel_launch(void* const* d_in, const int* in_sizes, int n_in,
                              void* d_out, int out_size, void* d_ws, size_t ws_size,
                              hipStream_t stream) {
    const float* X    = (const float*)d_in[0];   // (4,2048,64)
    const float* mem0 = (const float*)d_in[1];   // (4096,)
    const float* opt  = (const float*)d_in[2];   // (25,)
    const float* Wq   = (const float*)d_in[3];   // (64,64)
    float* out = (float*)d_out;

    tnt_fused<<<dim3(NBLK), dim3(NTHR), 0, stream>>>(X, mem0, opt, Wq, out);
}